// Round 20
// baseline (125.909 us; speedup 1.0000x reference)
//
#include <hip/hip_runtime.h>
#include <math.h>

#define N_SAMP 4096
#define NS     7
#define DT_F   1e-5f
#define B0_F   80.0f
#define T2_F   1.0f
#define SW_F   1000.0f
#define TWO_PI 6.2831853071795864769f

// ws layout (floats): Vt 0..16384 | lam 16384..16512 | U 16512..32896 |
//                     wc 49280..52352 | ab(int) 52352..55424 |
//                     fidf(float2) 65664..73856 | part 73856..139392
// out (f32, 24576): ReFID [0,4096) | time [4096,8192) |
//                   Re shifted spec [8192,16384) | freq [16384,24576)

// Register-resident one-sided Jacobi per sector (one wave per sector).
// B = A_sector + SIGMA*I (PSD). Columns in registers, pair exchange via shfl.
// __launch_bounds__(64, 1): 1 wave/EU floor -> full 512-VGPR budget, no spill
// (r19 spilled at VGPR_Count=52 and went through scratch).
__global__ __launch_bounds__(64, 1) void k_eig(const float* __restrict__ h,
                                               float* __restrict__ Vt_full,
                                               float* __restrict__ U,
                                               float* __restrict__ lam_out) {
    const int nsz_[8]   = {1, 7, 21, 35, 35, 21, 7, 1};
    const int nbase_[8] = {0, 1, 8, 29, 64, 99, 120, 127};
    const int s    = blockIdx.x;
    const int ns   = nsz_[s];
    const int base = nbase_[s];
    const int lane = threadIdx.x;
    const int m    = ns + 1;          // even; column m-1 is zero padding
    const int nr   = ns;              // rounds in one sweep

    __shared__ float hs[49];
    __shared__ int   st[36];
    __shared__ int   inv2[128];
    __shared__ float vrow[36][37];

    if (lane < 49) hs[lane] = h[lane];
    if (lane == 0) {
        int cnt = 0;
        for (int r = 0; r < 128; ++r) if (__popc(r) == s) st[cnt++] = r;
    }
    __syncthreads();
    if (lane < ns) inv2[st[lane]] = lane;
    __syncthreads();

    const float SIGMA = 10000.0f;
    float B[36];
#pragma unroll
    for (int i = 0; i < 36; ++i) B[i] = 0.f;
    if (lane < ns) {
        int cst = st[lane];
#pragma unroll
        for (int i = 0; i < 36; ++i) {
            if (i < ns) {
                int r = st[i];
                float val = 0.f;
                if (r == cst) {
                    float acc = 0.f;
                    for (int a = 0; a < 7; ++a) {
                        float za = ((r >> (6 - a)) & 1) ? -0.5f : 0.5f;
                        acc += B0_F * hs[a * 7 + a] * za;
                        for (int b = a + 1; b < 7; ++b) {
                            float zb = ((r >> (6 - b)) & 1) ? -0.5f : 0.5f;
                            acc += hs[a * 7 + b] * za * zb;
                        }
                    }
                    val = TWO_PI * acc + SIGMA;
                } else {
                    int x = r ^ cst;
                    if (__popc(x) == 2) {
                        int u = 31 - __clz(x);
                        int v = __ffs(x) - 1;
                        if (((r >> u) & 1) != ((r >> v) & 1))
                            val = TWO_PI * 0.5f * hs[(6 - u) * 7 + (6 - v)];
                    }
                }
                B[i] = val;
            }
        }
    }

    for (int t = 0; t < nr; ++t) {
        // tournament partner (mutual): fixed player m-1 pairs with t
        int pj;
        if (lane >= m) pj = lane;
        else if (lane == m - 1) pj = t;
        else {
            int pos = lane - t; if (pos < 0) pos += nr;
            if (pos == 0) pj = m - 1;
            else { int pp = (2 * t - lane) % nr; if (pp < 0) pp += nr; pj = pp; }
        }
        // exchange partner's column
        float C[36];
#pragma unroll
        for (int e = 0; e < 36; ++e) C[e] = __shfl(B[e], pj);
        // alpha = ||own||^2, gamma = own . partner  (bitwise-identical on both lanes)
        float a0=0,a1=0,a2=0,a3=0, g0=0,g1=0,g2=0,g3=0;
#pragma unroll
        for (int e = 0; e < 36; e += 4) {
            a0 += B[e]   * B[e];   g0 += B[e]   * C[e];
            a1 += B[e+1] * B[e+1]; g1 += B[e+1] * C[e+1];
            a2 += B[e+2] * B[e+2]; g2 += B[e+2] * C[e+2];
            a3 += B[e+3] * B[e+3]; g3 += B[e+3] * C[e+3];
        }
        float alpha = (a0 + a1) + (a2 + a3);
        float gamma = (g0 + g1) + (g2 + g3);
        float beta  = __shfl(alpha, pj);
        bool active = (lane < ns) && (pj < ns) && (pj != lane);
        if (active && fabsf(gamma) >= 1e-20f) {
            bool amin = lane < pj;
            float amn = amin ? alpha : beta;
            float amx = amin ? beta  : alpha;
            float tau = (amx - amn) / (2.f * gamma);
            float tt  = copysignf(1.f / (fabsf(tau) + sqrtf(1.f + tau * tau)), tau);
            float c   = rsqrtf(1.f + tt * tt);
            float sn  = tt * c;
            float sgn = amin ? -sn : sn;   // min: c*B - sn*C ; max: c*B + sn*C
#pragma unroll
            for (int e = 0; e < 36; ++e) B[e] = c * B[e] + sgn * C[e];
        }
    }

    // eigenvalues and eigenvectors from converged columns
    float n0=0,n1=0,n2=0,n3=0;
#pragma unroll
    for (int e = 0; e < 36; e += 4) {
        n0 += B[e]*B[e]; n1 += B[e+1]*B[e+1]; n2 += B[e+2]*B[e+2]; n3 += B[e+3]*B[e+3];
    }
    float norm2 = (n0 + n1) + (n2 + n3);
    if (lane < ns) {
        float nrm   = sqrtf(norm2);
        float inorm = 1.f / nrm;
        lam_out[base + lane] = nrm - SIGMA;
#pragma unroll
        for (int i = 0; i < 36; ++i) vrow[lane][i] = B[i] * inorm;
    }
    __syncthreads();
    // coalesced writeback of Vt rows + fused U rows (from vrow LDS)
    for (int a = 0; a < ns; ++a) {
        for (int rr = lane; rr < 128; rr += 64) {
            int pc = __popc(rr);
            float v = (pc == s) ? vrow[a][inv2[rr]] : 0.f;
            Vt_full[(base + a) * 128 + rr] = v;
            float uval = 0.f;
            if (pc == s - 1) {
#pragma unroll
                for (int p = 0; p < 7; ++p)
                    if (!((rr >> p) & 1)) uval += vrow[a][inv2[rr + (1 << p)]];
            }
            U[(base + a) * 128 + rr] = uval;
        }
    }
}

// Compact W: only sector-pair (s -> s+1) entries are nonzero; 3003 entries,
// padded to 3072. wc[e] = 0.5*(Vt[a]·U[b])^2, ab[e] = (a<<7)|b.
__global__ __launch_bounds__(128) void k_mwc(const float* __restrict__ Vt,
                                             const float* __restrict__ U,
                                             float* __restrict__ wc,
                                             int* __restrict__ ab) {
    const int n2_[7]   = {7, 21, 35, 35, 21, 7, 1};
    const int offs_[7] = {0, 7, 154, 889, 2114, 2849, 2996};
    const int nb1_[7]  = {0, 1, 8, 29, 64, 99, 120};
    const int nb2_[7]  = {1, 8, 29, 64, 99, 120, 127};
    int e = blockIdx.x * 128 + threadIdx.x;
    if (e >= 3072) return;
    if (e >= 3003) { wc[e] = 0.f; ab[e] = 0; return; }
    int s = 0;
#pragma unroll
    for (int t = 1; t < 7; ++t) if (e >= offs_[t]) s = t;
    int loc = e - offs_[s];
    int i = loc / n2_[s];
    int j = loc - i * n2_[s];
    int a = nb1_[s] + i, b = nb2_[s] + j;
    float acc = 0.f;
    for (int r = 0; r < 128; ++r) acc += Vt[a * 128 + r] * U[b * 128 + r];
    wc[e] = 0.5f * acc * acc;
    ab[e] = (a << 7) | b;
}

// 8 samples per block via phasor recurrence over the 3072 compact entries
__global__ __launch_bounds__(256) void k_fid(const float* __restrict__ wc,
                                             const int* __restrict__ ab,
                                             const float* __restrict__ lam,
                                             float* __restrict__ fidfF,
                                             float* __restrict__ out) {
    __shared__ float2 cb0[128], dd[128];
    __shared__ float  lred[4][16];
    const int n0  = blockIdx.x * 8;
    const int tid = threadIdx.x;
    const float t0 = (float)n0 * DT_F;
    if (tid < 128) {
        float sn, cs;
        sincosf(lam[tid] * t0, &sn, &cs);
        cb0[tid] = make_float2(cs, -sn);
        sincosf(lam[tid] * DT_F, &sn, &cs);
        dd[tid] = make_float2(cs, -sn);
    }
    __syncthreads();

    float ar0=0,ar1=0,ar2=0,ar3=0,ar4=0,ar5=0,ar6=0,ar7=0;
    float ai0=0,ai1=0,ai2=0,ai3=0,ai4=0,ai5=0,ai6=0,ai7=0;
#pragma unroll 4
    for (int i = 0; i < 12; ++i) {
        int e = i * 256 + tid;
        float w = wc[e];
        int pq = ab[e];
        int a = pq >> 7, b = pq & 127;
        float2 ca = cb0[a], cbv = cb0[b];
        float2 da = dd[a],  db  = dd[b];
        float zr = ca.x * cbv.x + ca.y * cbv.y;
        float zi = ca.x * cbv.y - ca.y * cbv.x;
        float fr = da.x * db.x + da.y * db.y;
        float fi = da.x * db.y - da.y * db.x;
        ar0 += w * zr; ai0 += w * zi; { float tr = zr*fr - zi*fi; zi = zr*fi + zi*fr; zr = tr; }
        ar1 += w * zr; ai1 += w * zi; { float tr = zr*fr - zi*fi; zi = zr*fi + zi*fr; zr = tr; }
        ar2 += w * zr; ai2 += w * zi; { float tr = zr*fr - zi*fi; zi = zr*fi + zi*fr; zr = tr; }
        ar3 += w * zr; ai3 += w * zi; { float tr = zr*fr - zi*fi; zi = zr*fi + zi*fr; zr = tr; }
        ar4 += w * zr; ai4 += w * zi; { float tr = zr*fr - zi*fi; zi = zr*fi + zi*fr; zr = tr; }
        ar5 += w * zr; ai5 += w * zi; { float tr = zr*fr - zi*fi; zi = zr*fi + zi*fr; zr = tr; }
        ar6 += w * zr; ai6 += w * zi; { float tr = zr*fr - zi*fi; zi = zr*fi + zi*fr; zr = tr; }
        ar7 += w * zr; ai7 += w * zi;
    }

    const int wave = tid >> 6, lane = tid & 63;
    float acc[16] = {ar0,ai0,ar1,ai1,ar2,ai2,ar3,ai3,ar4,ai4,ar5,ai5,ar6,ai6,ar7,ai7};
#pragma unroll 16
    for (int v = 0; v < 16; ++v) {
        float x = acc[v];
        for (int off = 32; off > 0; off >>= 1) x += __shfl_down(x, off);
        if (lane == 0) lred[wave][v] = x;
    }
    __syncthreads();
    if (tid < 16) {
        float x = lred[0][tid] + lred[1][tid] + lred[2][tid] + lred[3][tid];
        int jj = tid >> 1, c = tid & 1;
        int n = n0 + jj;
        float ap = expf(-(DT_F / T2_F) * (float)n);
        x *= ap;
        fidfF[2 * n + c] = x;
        if (c == 0) out[n] = x;
    }
}

// split-K shifted-spectrum partials: 8 chunks x 32 k-groups
__global__ __launch_bounds__(256) void k_dft(const float2* __restrict__ fidf,
                                             float* __restrict__ part) {
    __shared__ float2 fs[512];
    const int tid = threadIdx.x;
    const int ch  = blockIdx.x >> 5;
    const int kb  = blockIdx.x & 31;
    const int n0  = ch * 512;
    fs[tid]       = fidf[n0 + tid];
    fs[tid + 256] = fidf[n0 + tid + 256];
    __syncthreads();
    const int k = kb * 256 + tid;
    const int K = (k + 4096) & 8191;
    const float C = TWO_PI / 8192.0f;
    int idx = (n0 * K) & 8191;
    float ar = 0.f;
    for (int i = 0; i < 512; ++i) {
        float2 s = fs[i];
        float sn, cs;
        __sincosf(C * (float)idx, &sn, &cs);
        ar += s.x * cs + s.y * sn;
        idx = (idx + K) & 8191;
    }
    part[ch * 8192 + k] = ar;
}

// reduce partials + write axes
__global__ void k_dredax(const float* __restrict__ part, float* __restrict__ out) {
    int i = blockIdx.x * 256 + threadIdx.x;   // 0..8191
    float s = 0.f;
#pragma unroll
    for (int ch = 0; ch < 8; ++ch) s += part[ch * 8192 + i];
    out[8192 + i] = s;
    out[16384 + i] = -0.5f * SW_F + (float)i * (SW_F / (float)(2 * N_SAMP - 1));
    if (i < N_SAMP)
        out[4096 + i] = (float)i * ((N_SAMP / SW_F) / (float)(N_SAMP - 1));
}

extern "C" void kernel_launch(void* const* d_in, const int* in_sizes, int n_in,
                              void* d_out, int out_size, void* d_ws, size_t ws_size,
                              hipStream_t stream) {
    const float* h = (const float*)d_in[0];
    float* out = (float*)d_out;
    float* ws  = (float*)d_ws;

    float*  Vt   = ws;
    float*  lam  = ws + 16384;
    float*  U    = ws + 16512;
    float*  wc   = ws + 49280;
    int*    ab   = (int*)(ws + 52352);
    float*  fidfF= ws + 65664;
    float2* fidf = (float2*)(ws + 65664);
    float*  part = ws + 73856;

    k_eig<<<8, 64, 0, stream>>>(h, Vt, U, lam);
    k_mwc<<<24, 128, 0, stream>>>(Vt, U, wc, ab);
    k_fid<<<512, 256, 0, stream>>>(wc, ab, lam, fidfF, out);
    k_dft<<<256, 256, 0, stream>>>(fidf, part);
    k_dredax<<<32, 256, 0, stream>>>(part, out);
}

// Round 21
// 125.600 us; speedup vs baseline: 1.0025x; 1.0025x over previous
//
#include <hip/hip_runtime.h>
#include <math.h>

#define N_SAMP 4096
#define NS     7
#define DT_F   1e-5f
#define B0_F   80.0f
#define T2_F   1.0f
#define SW_F   1000.0f
#define TWO_PI 6.2831853071795864769f

// ws layout (floats): Vt 0..16384 | lam 16384..16512 | U 16512..32896 |
//                     wc 49280..52352 | ab(int) 52352..55424 |
//                     fidf(float2) 65664..73856 | part 73856..139392
// out (f32, 24576): ReFID [0,4096) | time [4096,8192) |
//                   Re shifted spec [8192,16384) | freq [16384,24576)

#define FOR36(X) X(0) X(1) X(2) X(3) X(4) X(5) X(6) X(7) X(8) X(9) X(10) X(11) \
  X(12) X(13) X(14) X(15) X(16) X(17) X(18) X(19) X(20) X(21) X(22) X(23) \
  X(24) X(25) X(26) X(27) X(28) X(29) X(30) X(31) X(32) X(33) X(34) X(35)

// Register-resident one-sided Jacobi per sector (one wave per sector).
// B = A_sector + SIGMA*I (PSD). Column held in 36 NAMED SCALARS (rule #20:
// arrays failed SROA -> scratch at 52 VGPR in r19/r20). Exchange via fused
// per-element __shfl; branchless rotation keeps shfl convergent.
__global__ __launch_bounds__(64, 1)
__attribute__((amdgpu_waves_per_eu(1, 2)))
void k_eig(const float* __restrict__ h,
           float* __restrict__ Vt_full,
           float* __restrict__ U,
           float* __restrict__ lam_out) {
    const int nsz_[8]   = {1, 7, 21, 35, 35, 21, 7, 1};
    const int nbase_[8] = {0, 1, 8, 29, 64, 99, 120, 127};
    const int s    = blockIdx.x;
    const int ns   = nsz_[s];
    const int base = nbase_[s];
    const int lane = threadIdx.x;
    const int m    = ns + 1;          // even; column m-1 is zero padding
    const int nr   = ns;              // rounds in one full sweep

    __shared__ float As[36 * 37];     // sector matrix, then reused as vrow
    __shared__ float hs[49];
    __shared__ int   st[36];
    __shared__ int   inv2[128];

    if (lane < 49) hs[lane] = h[lane];
    if (lane == 0) {
        int cnt = 0;
        for (int r = 0; r < 128; ++r) if (__popc(r) == s) st[cnt++] = r;
    }
    for (int t = lane; t < 36 * 37; t += 64) As[t] = 0.f;
    __syncthreads();
    if (lane < ns) inv2[st[lane]] = lane;

    const float SIGMA = 10000.0f;
    // cooperative build of A_sector + SIGMA*I into As[i*37+j]
    for (int e = lane; e < ns * ns; e += 64) {
        int i = e / ns, j = e - (e / ns) * ns;
        int r = st[i], c = st[j];
        float val = 0.f;
        if (r == c) {
            float acc = 0.f;
            for (int a = 0; a < 7; ++a) {
                float za = ((r >> (6 - a)) & 1) ? -0.5f : 0.5f;
                acc += B0_F * hs[a * 7 + a] * za;
                for (int b = a + 1; b < 7; ++b) {
                    float zb = ((r >> (6 - b)) & 1) ? -0.5f : 0.5f;
                    acc += hs[a * 7 + b] * za * zb;
                }
            }
            val = TWO_PI * acc + SIGMA;
        } else {
            int x = r ^ c;
            if (__popc(x) == 2) {
                int u = 31 - __clz(x);
                int v = __ffs(x) - 1;
                if (((r >> u) & 1) != ((r >> v) & 1))
                    val = TWO_PI * 0.5f * hs[(6 - u) * 7 + (6 - v)];
            }
        }
        As[i * 37 + j] = val;
    }
    __syncthreads();

    // load own column into named scalars (compile-time row offsets)
#define DECLB(i) float B##i = 0.f;
    FOR36(DECLB)
#undef DECLB
    if (lane < 36) {
#define LOADB(i) B##i = As[(i) * 37 + lane];
        FOR36(LOADB)
#undef LOADB
    }

    for (int t = 0; t < nr; ++t) {
        // tournament partner (mutual): fixed player m-1 pairs with t
        int pj;
        if (lane >= m) pj = lane;
        else if (lane == m - 1) pj = t;
        else {
            int pos = lane - t; if (pos < 0) pos += nr;
            if (pos == 0) pj = m - 1;
            else { int pp = (2 * t - lane) % nr; if (pp < 0) pp += nr; pj = pp; }
        }
        // pass 1: alpha = ||own||^2, gamma = own . partner (bitwise-equal on pair)
        float alpha = 0.f, gamma = 0.f;
#define GAMB(i) { float t_ = __shfl(B##i, pj); gamma += B##i * t_; alpha += B##i * B##i; }
        FOR36(GAMB)
#undef GAMB
        float beta = __shfl(alpha, pj);
        // branchless rotation coefficients (inactive -> identity)
        float cr = 1.f, sgn = 0.f;
        bool active = (lane < ns) && (pj < ns) && (pj != lane);
        if (active && fabsf(gamma) >= 1e-20f) {
            bool amin = lane < pj;
            float amn = amin ? alpha : beta;
            float amx = amin ? beta  : alpha;
            float tau = (amx - amn) / (2.f * gamma);
            float tt  = copysignf(1.f / (fabsf(tau) + sqrtf(1.f + tau * tau)), tau);
            float c   = rsqrtf(1.f + tt * tt);
            float sn  = tt * c;
            cr  = c;
            sgn = amin ? -sn : sn;   // min: c*B - sn*C ; max: c*B + sn*C
        }
        // pass 2: rotate (shfl reads pre-update values in lockstep)
#define ROTB(i) { float t_ = __shfl(B##i, pj); B##i = cr * B##i + sgn * t_; }
        FOR36(ROTB)
#undef ROTB
    }

    // eigenvalues + normalized eigenvectors from converged columns
    float nrm2 = 0.f;
#define NRMB(i) nrm2 += B##i * B##i;
    FOR36(NRMB)
#undef NRMB
    __syncthreads();   // all reads of As done; safe to overwrite as vrow
    if (lane < ns) {
        float nrm   = sqrtf(nrm2);
        float inorm = 1.f / nrm;
        lam_out[base + lane] = nrm - SIGMA;
#define WBB(i) As[lane * 37 + (i)] = B##i * inorm;
        FOR36(WBB)
#undef WBB
    }
    __syncthreads();
    // coalesced writeback of Vt rows + fused U rows (from vrow=As LDS)
    for (int a = 0; a < ns; ++a) {
        for (int rr = lane; rr < 128; rr += 64) {
            int pc = __popc(rr);
            float v = (pc == s) ? As[a * 37 + inv2[rr]] : 0.f;
            Vt_full[(base + a) * 128 + rr] = v;
            float uval = 0.f;
            if (pc == s - 1) {
#pragma unroll
                for (int p = 0; p < 7; ++p)
                    if (!((rr >> p) & 1)) uval += As[a * 37 + inv2[rr + (1 << p)]];
            }
            U[(base + a) * 128 + rr] = uval;
        }
    }
}

// Compact W: only sector-pair (s -> s+1) entries are nonzero; 3003 entries,
// padded to 3072. wc[e] = 0.5*(Vt[a]·U[b])^2, ab[e] = (a<<7)|b.
__global__ __launch_bounds__(128) void k_mwc(const float* __restrict__ Vt,
                                             const float* __restrict__ U,
                                             float* __restrict__ wc,
                                             int* __restrict__ ab) {
    const int n2_[7]   = {7, 21, 35, 35, 21, 7, 1};
    const int offs_[7] = {0, 7, 154, 889, 2114, 2849, 2996};
    const int nb1_[7]  = {0, 1, 8, 29, 64, 99, 120};
    const int nb2_[7]  = {1, 8, 29, 64, 99, 120, 127};
    int e = blockIdx.x * 128 + threadIdx.x;
    if (e >= 3072) return;
    if (e >= 3003) { wc[e] = 0.f; ab[e] = 0; return; }
    int s = 0;
#pragma unroll
    for (int t = 1; t < 7; ++t) if (e >= offs_[t]) s = t;
    int loc = e - offs_[s];
    int i = loc / n2_[s];
    int j = loc - i * n2_[s];
    int a = nb1_[s] + i, b = nb2_[s] + j;
    float acc = 0.f;
    for (int r = 0; r < 128; ++r) acc += Vt[a * 128 + r] * U[b * 128 + r];
    wc[e] = 0.5f * acc * acc;
    ab[e] = (a << 7) | b;
}

// 8 samples per block via phasor recurrence over the 3072 compact entries
__global__ __launch_bounds__(256) void k_fid(const float* __restrict__ wc,
                                             const int* __restrict__ ab,
                                             const float* __restrict__ lam,
                                             float* __restrict__ fidfF,
                                             float* __restrict__ out) {
    __shared__ float2 cb0[128], dd[128];
    __shared__ float  lred[4][16];
    const int n0  = blockIdx.x * 8;
    const int tid = threadIdx.x;
    const float t0 = (float)n0 * DT_F;
    if (tid < 128) {
        float sn, cs;
        sincosf(lam[tid] * t0, &sn, &cs);
        cb0[tid] = make_float2(cs, -sn);
        sincosf(lam[tid] * DT_F, &sn, &cs);
        dd[tid] = make_float2(cs, -sn);
    }
    __syncthreads();

    float ar0=0,ar1=0,ar2=0,ar3=0,ar4=0,ar5=0,ar6=0,ar7=0;
    float ai0=0,ai1=0,ai2=0,ai3=0,ai4=0,ai5=0,ai6=0,ai7=0;
#pragma unroll 4
    for (int i = 0; i < 12; ++i) {
        int e = i * 256 + tid;
        float w = wc[e];
        int pq = ab[e];
        int a = pq >> 7, b = pq & 127;
        float2 ca = cb0[a], cbv = cb0[b];
        float2 da = dd[a],  db  = dd[b];
        float zr = ca.x * cbv.x + ca.y * cbv.y;
        float zi = ca.x * cbv.y - ca.y * cbv.x;
        float fr = da.x * db.x + da.y * db.y;
        float fi = da.x * db.y - da.y * db.x;
        ar0 += w * zr; ai0 += w * zi; { float tr = zr*fr - zi*fi; zi = zr*fi + zi*fr; zr = tr; }
        ar1 += w * zr; ai1 += w * zi; { float tr = zr*fr - zi*fi; zi = zr*fi + zi*fr; zr = tr; }
        ar2 += w * zr; ai2 += w * zi; { float tr = zr*fr - zi*fi; zi = zr*fi + zi*fr; zr = tr; }
        ar3 += w * zr; ai3 += w * zi; { float tr = zr*fr - zi*fi; zi = zr*fi + zi*fr; zr = tr; }
        ar4 += w * zr; ai4 += w * zi; { float tr = zr*fr - zi*fi; zi = zr*fi + zi*fr; zr = tr; }
        ar5 += w * zr; ai5 += w * zi; { float tr = zr*fr - zi*fi; zi = zr*fi + zi*fr; zr = tr; }
        ar6 += w * zr; ai6 += w * zi; { float tr = zr*fr - zi*fi; zi = zr*fi + zi*fr; zr = tr; }
        ar7 += w * zr; ai7 += w * zi;
    }

    const int wave = tid >> 6, lane = tid & 63;
    float acc[16] = {ar0,ai0,ar1,ai1,ar2,ai2,ar3,ai3,ar4,ai4,ar5,ai5,ar6,ai6,ar7,ai7};
#pragma unroll 16
    for (int v = 0; v < 16; ++v) {
        float x = acc[v];
        for (int off = 32; off > 0; off >>= 1) x += __shfl_down(x, off);
        if (lane == 0) lred[wave][v] = x;
    }
    __syncthreads();
    if (tid < 16) {
        float x = lred[0][tid] + lred[1][tid] + lred[2][tid] + lred[3][tid];
        int jj = tid >> 1, c = tid & 1;
        int n = n0 + jj;
        float ap = expf(-(DT_F / T2_F) * (float)n);
        x *= ap;
        fidfF[2 * n + c] = x;
        if (c == 0) out[n] = x;
    }
}

// split-K shifted-spectrum partials: 8 chunks x 32 k-groups
__global__ __launch_bounds__(256) void k_dft(const float2* __restrict__ fidf,
                                             float* __restrict__ part) {
    __shared__ float2 fs[512];
    const int tid = threadIdx.x;
    const int ch  = blockIdx.x >> 5;
    const int kb  = blockIdx.x & 31;
    const int n0  = ch * 512;
    fs[tid]       = fidf[n0 + tid];
    fs[tid + 256] = fidf[n0 + tid + 256];
    __syncthreads();
    const int k = kb * 256 + tid;
    const int K = (k + 4096) & 8191;
    const float C = TWO_PI / 8192.0f;
    int idx = (n0 * K) & 8191;
    float ar = 0.f;
    for (int i = 0; i < 512; ++i) {
        float2 s = fs[i];
        float sn, cs;
        __sincosf(C * (float)idx, &sn, &cs);
        ar += s.x * cs + s.y * sn;
        idx = (idx + K) & 8191;
    }
    part[ch * 8192 + k] = ar;
}

// reduce partials + write axes
__global__ void k_dredax(const float* __restrict__ part, float* __restrict__ out) {
    int i = blockIdx.x * 256 + threadIdx.x;   // 0..8191
    float s = 0.f;
#pragma unroll
    for (int ch = 0; ch < 8; ++ch) s += part[ch * 8192 + i];
    out[8192 + i] = s;
    out[16384 + i] = -0.5f * SW_F + (float)i * (SW_F / (float)(2 * N_SAMP - 1));
    if (i < N_SAMP)
        out[4096 + i] = (float)i * ((N_SAMP / SW_F) / (float)(N_SAMP - 1));
}

extern "C" void kernel_launch(void* const* d_in, const int* in_sizes, int n_in,
                              void* d_out, int out_size, void* d_ws, size_t ws_size,
                              hipStream_t stream) {
    const float* h = (const float*)d_in[0];
    float* out = (float*)d_out;
    float* ws  = (float*)d_ws;

    float*  Vt   = ws;
    float*  lam  = ws + 16384;
    float*  U    = ws + 16512;
    float*  wc   = ws + 49280;
    int*    ab   = (int*)(ws + 52352);
    float*  fidfF= ws + 65664;
    float2* fidf = (float2*)(ws + 65664);
    float*  part = ws + 73856;

    k_eig<<<8, 64, 0, stream>>>(h, Vt, U, lam);
    k_mwc<<<24, 128, 0, stream>>>(Vt, U, wc, ab);
    k_fid<<<512, 256, 0, stream>>>(wc, ab, lam, fidfF, out);
    k_dft<<<256, 256, 0, stream>>>(fidf, part);
    k_dredax<<<32, 256, 0, stream>>>(part, out);
}